// Round 1
// baseline (1323.522 us; speedup 1.0000x reference)
//
#include <hip/hip_runtime.h>
#include <math.h>

#define N_NODES 50000
#define N_EDGES 800000
#define ND 128
#define ED 16
#define H1 256
#define H2 32
#define NEG_SLOPE 0.2f

// ---------------------------------------------------------------- K1: counts + loop_attr sums
__global__ void k_count_loop(const int* __restrict__ ei, const float* __restrict__ ea,
                             int* __restrict__ counts, float* __restrict__ loop_sum, int E) {
    int total = E * ED;
    for (int idx = blockIdx.x * blockDim.x + threadIdx.x; idx < total;
         idx += gridDim.x * blockDim.x) {
        int e = idx >> 4, d = idx & 15;
        int dst = ei[E + e];
        atomicAdd(&loop_sum[dst * ED + d], ea[idx]);
        if (d == 0) atomicAdd(&counts[dst], 1);
    }
}

// ---------------------------------------------------------------- K2: exclusive scan -> rowptr
__global__ void k_scan_rowptr(const int* __restrict__ counts, int* __restrict__ rowptr, int n) {
    __shared__ int sh[1024];
    __shared__ int carry;
    if (threadIdx.x == 0) carry = 0;
    __syncthreads();
    for (int base = 0; base < n; base += 1024) {
        int i = base + threadIdx.x;
        int v = (i < n) ? counts[i] + 1 : 0;  // +1 self loop
        sh[threadIdx.x] = v;
        __syncthreads();
        for (int off = 1; off < 1024; off <<= 1) {
            int t = (threadIdx.x >= off) ? sh[threadIdx.x - off] : 0;
            __syncthreads();
            sh[threadIdx.x] += t;
            __syncthreads();
        }
        if (i < n) rowptr[i + 1] = carry + sh[threadIdx.x];
        __syncthreads();
        if (threadIdx.x == 1023) carry += sh[1023];
        __syncthreads();
    }
    if (threadIdx.x == 0) rowptr[0] = 0;
}

// ---------------------------------------------------------------- K2b: loop_attr = sum/deg
__global__ void k_finalize_loop(float* __restrict__ loop_sum, const int* __restrict__ counts, int n) {
    int total = n * ED;
    for (int idx = blockIdx.x * blockDim.x + threadIdx.x; idx < total;
         idx += gridDim.x * blockDim.x) {
        int i = idx >> 4;
        int c = counts[i];
        loop_sum[idx] /= (float)(c > 1 ? c : 1);
    }
}

// ---------------------------------------------------------------- K3: fill CSR
__global__ void k_fill_csr(const int* __restrict__ ei, const int* __restrict__ rowptr,
                           int* __restrict__ fill, int* __restrict__ csr_src,
                           int* __restrict__ csr_eid, int E, int n) {
    int total = E + n;
    for (int idx = blockIdx.x * blockDim.x + threadIdx.x; idx < total;
         idx += gridDim.x * blockDim.x) {
        if (idx < E) {
            int dst = ei[E + idx];
            int slot = rowptr[dst] + atomicAdd(&fill[dst], 1);
            csr_src[slot] = ei[idx];
            csr_eid[slot] = idx;
        } else {
            int i = idx - E;
            int slot = rowptr[i + 1] - 1;   // last slot reserved for self loop
            csr_src[slot] = i;
            csr_eid[slot] = E + i;
        }
    }
}

// ---------------------------------------------------------------- K4: Y[n][C] = X[n][K] @ W[C][K]^T + b
#define GT 64
#define GK 32
__global__ __launch_bounds__(256) void k_gemm_xwt(const float* __restrict__ X,
                                                  const float* __restrict__ W,
                                                  const float* __restrict__ bias,
                                                  float* __restrict__ Y,
                                                  int n, int K, int C) {
    __shared__ float xs[GT][GK + 1];
    __shared__ float ws[GT][GK + 1];
    int tid = threadIdx.x;
    int tx = tid & 15, ty = tid >> 4;
    int row0 = blockIdx.x * GT, col0 = blockIdx.y * GT;
    float acc[4][4] = {};
    for (int k0 = 0; k0 < K; k0 += GK) {
        #pragma unroll
        for (int l = 0; l < (GT * GK) / 256; ++l) {
            int idx = l * 256 + tid;
            int r = idx >> 5, kk = idx & 31;
            int gr = row0 + r;
            xs[r][kk] = (gr < n) ? X[(size_t)gr * K + k0 + kk] : 0.f;
            int gc = col0 + r;
            ws[r][kk] = (gc < C) ? W[(size_t)gc * K + k0 + kk] : 0.f;
        }
        __syncthreads();
        #pragma unroll
        for (int kk = 0; kk < GK; ++kk) {
            float a[4], b[4];
            #pragma unroll
            for (int i = 0; i < 4; ++i) a[i] = xs[ty * 4 + i][kk];
            #pragma unroll
            for (int j = 0; j < 4; ++j) b[j] = ws[tx * 4 + j][kk];
            #pragma unroll
            for (int i = 0; i < 4; ++i)
                #pragma unroll
                for (int j = 0; j < 4; ++j) acc[i][j] += a[i] * b[j];
        }
        __syncthreads();
    }
    #pragma unroll
    for (int i = 0; i < 4; ++i) {
        int r = row0 + ty * 4 + i;
        if (r >= n) continue;
        #pragma unroll
        for (int j = 0; j < 4; ++j) {
            int c = col0 + tx * 4 + j;
            if (c < C) Y[(size_t)r * C + c] = acc[i][j] + bias[c];
        }
    }
}

// ---------------------------------------------------------------- K5: layer-1 aggregate (one block / node)
__global__ __launch_bounds__(256) void k_gat_h1(const float* __restrict__ xl,
                                                const float* __restrict__ xr,
                                                const float* __restrict__ edge_attr,
                                                const float* __restrict__ loop_attr,
                                                const float* __restrict__ We,
                                                const float* __restrict__ att,
                                                const float* __restrict__ bias,
                                                const int* __restrict__ rowptr,
                                                const int* __restrict__ csr_src,
                                                const int* __restrict__ csr_eid,
                                                float* __restrict__ out, int E) {
    const int node = blockIdx.x;
    const int c = threadIdx.x;
    __shared__ float eaS[ED];
    __shared__ float red[4];
    float4 wv[4];
    #pragma unroll
    for (int q = 0; q < 4; ++q) wv[q] = ((const float4*)We)[c * 4 + q];
    float attc = att[c];
    float xrc = xr[(size_t)node * H1 + c];
    int beg = rowptr[node], end = rowptr[node + 1];
    int lane = c & 63, wid = c >> 6;
    float m_run = -INFINITY, denom = 0.f, acc = 0.f;
    for (int j = beg; j < end; ++j) {
        int s = csr_src[j];
        int eid = csr_eid[j];
        const float* ea = (eid < E) ? edge_attr + (size_t)eid * ED
                                    : loop_attr + (size_t)(eid - E) * ED;
        __syncthreads();
        if (c < ED) eaS[c] = ea[c];
        __syncthreads();
        float we = 0.f;
        #pragma unroll
        for (int q = 0; q < 4; ++q)
            we += wv[q].x * eaS[4 * q] + wv[q].y * eaS[4 * q + 1] +
                  wv[q].z * eaS[4 * q + 2] + wv[q].w * eaS[4 * q + 3];
        float xls = xl[(size_t)s * H1 + c];
        float m = xls + xrc + we;
        m = (m > 0.f) ? m : NEG_SLOPE * m;
        float p = attc * m;
        #pragma unroll
        for (int off = 32; off >= 1; off >>= 1) p += __shfl_xor(p, off);
        if (lane == 0) red[wid] = p;
        __syncthreads();
        float logit = red[0] + red[1] + red[2] + red[3];
        float newm = fmaxf(m_run, logit);
        float scale = __expf(m_run - newm);
        float pe = __expf(logit - newm);
        denom = denom * scale + pe;
        acc = acc * scale + pe * xls;
        m_run = newm;
    }
    out[(size_t)node * H1 + c] = acc / denom + bias[c];
}

// ---------------------------------------------------------------- K7: layer-2 aggregate (one wave / node)
__global__ __launch_bounds__(64) void k_gat_h2(const float* __restrict__ xl,
                                               const float* __restrict__ xr,
                                               const float* __restrict__ edge_attr,
                                               const float* __restrict__ loop_attr,
                                               const float* __restrict__ We,
                                               const float* __restrict__ att,
                                               const float* __restrict__ bias,
                                               const int* __restrict__ rowptr,
                                               const int* __restrict__ csr_src,
                                               const int* __restrict__ csr_eid,
                                               float* __restrict__ out, int E) {
    const int node = blockIdx.x;
    const int tid = threadIdx.x;
    const int c = tid & 31;
    __shared__ float eaS[ED];
    float4 wv[4];
    #pragma unroll
    for (int q = 0; q < 4; ++q) wv[q] = ((const float4*)We)[c * 4 + q];
    float attc = att[c];
    float xrc = xr[(size_t)node * H2 + c];
    int beg = rowptr[node], end = rowptr[node + 1];
    float m_run = -INFINITY, denom = 0.f, acc = 0.f;
    for (int j = beg; j < end; ++j) {
        int s = csr_src[j];
        int eid = csr_eid[j];
        const float* ea = (eid < E) ? edge_attr + (size_t)eid * ED
                                    : loop_attr + (size_t)(eid - E) * ED;
        __syncthreads();
        if (tid < ED) eaS[tid] = ea[tid];
        __syncthreads();
        float we = 0.f;
        #pragma unroll
        for (int q = 0; q < 4; ++q)
            we += wv[q].x * eaS[4 * q] + wv[q].y * eaS[4 * q + 1] +
                  wv[q].z * eaS[4 * q + 2] + wv[q].w * eaS[4 * q + 3];
        float xls = xl[(size_t)s * H2 + c];
        float m = xls + xrc + we;
        m = (m > 0.f) ? m : NEG_SLOPE * m;
        float p = (tid < 32) ? attc * m : 0.f;
        #pragma unroll
        for (int off = 32; off >= 1; off >>= 1) p += __shfl_xor(p, off);
        float logit = p;
        float newm = fmaxf(m_run, logit);
        float scale = __expf(m_run - newm);
        float pe = __expf(logit - newm);
        denom = denom * scale + pe;
        acc = acc * scale + pe * xls;
        m_run = newm;
    }
    if (tid < 32) out[(size_t)node * H2 + c] = acc / denom + bias[c];
}

// ---------------------------------------------------------------- K8: mean over nodes
__global__ __launch_bounds__(256) void k_mean(const float* __restrict__ h2,
                                              float* __restrict__ out, int total, float invN) {
    __shared__ float red[H2];
    int tid = threadIdx.x;
    if (tid < H2) red[tid] = 0.f;
    __syncthreads();
    float part = 0.f;
    for (int idx = blockIdx.x * blockDim.x + tid; idx < total; idx += gridDim.x * blockDim.x)
        part += h2[idx];
    atomicAdd(&red[tid & 31], part);
    __syncthreads();
    if (tid < H2) atomicAdd(&out[tid], red[tid] * invN);
}

// ----------------------------------------------------------------
extern "C" void kernel_launch(void* const* d_in, const int* in_sizes, int n_in,
                              void* d_out, int out_size, void* d_ws, size_t ws_size,
                              hipStream_t stream) {
    const float* x   = (const float*)d_in[0];
    const int*   ei  = (const int*)d_in[1];
    const float* ea  = (const float*)d_in[2];
    const float* Wl1 = (const float*)d_in[3];
    const float* bl1 = (const float*)d_in[4];
    const float* Wr1 = (const float*)d_in[5];
    const float* br1 = (const float*)d_in[6];
    const float* We1 = (const float*)d_in[7];
    const float* at1 = (const float*)d_in[8];
    const float* bi1 = (const float*)d_in[9];
    const float* Wl2 = (const float*)d_in[10];
    const float* bl2 = (const float*)d_in[11];
    const float* Wr2 = (const float*)d_in[12];
    const float* br2 = (const float*)d_in[13];
    const float* We2 = (const float*)d_in[14];
    const float* at2 = (const float*)d_in[15];
    const float* bi2 = (const float*)d_in[16];
    float* out = (float*)d_out;

    const int N = N_NODES, E = N_EDGES, ET = N_EDGES + N_NODES;

    size_t off = 0;
    auto carve = [&](size_t bytes) {
        void* p = (char*)d_ws + off;
        off += (bytes + 255) & ~(size_t)255;
        return p;
    };
    int*   counts    = (int*)carve((size_t)N * 4);
    int*   fill      = (int*)carve((size_t)N * 4);
    int*   rowptr    = (int*)carve((size_t)(N + 1) * 4);
    float* loop_attr = (float*)carve((size_t)N * ED * 4);
    int*   csr_src   = (int*)carve((size_t)ET * 4);
    int*   csr_eid   = (int*)carve((size_t)ET * 4);
    float* xl1       = (float*)carve((size_t)N * H1 * 4);
    float* xr1       = (float*)carve((size_t)N * H1 * 4);
    float* h1        = (float*)carve((size_t)N * H1 * 4);
    float* xl2       = (float*)carve((size_t)N * H2 * 4);
    float* xr2       = (float*)carve((size_t)N * H2 * 4);
    float* h2        = (float*)carve((size_t)N * H2 * 4);

    hipMemsetAsync(counts, 0, (size_t)N * 4, stream);
    hipMemsetAsync(fill, 0, (size_t)N * 4, stream);
    hipMemsetAsync(loop_attr, 0, (size_t)N * ED * 4, stream);
    hipMemsetAsync(out, 0, (size_t)H2 * 4, stream);

    k_count_loop<<<8192, 256, 0, stream>>>(ei, ea, counts, loop_attr, E);
    k_scan_rowptr<<<1, 1024, 0, stream>>>(counts, rowptr, N);
    k_finalize_loop<<<(N * ED + 255) / 256, 256, 0, stream>>>(loop_attr, counts, N);
    k_fill_csr<<<(E + N + 255) / 256, 256, 0, stream>>>(ei, rowptr, fill, csr_src, csr_eid, E, N);

    dim3 g1((N + GT - 1) / GT, H1 / GT);
    k_gemm_xwt<<<g1, 256, 0, stream>>>(x, Wl1, bl1, xl1, N, ND, H1);
    k_gemm_xwt<<<g1, 256, 0, stream>>>(x, Wr1, br1, xr1, N, ND, H1);

    k_gat_h1<<<N, 256, 0, stream>>>(xl1, xr1, ea, loop_attr, We1, at1, bi1,
                                    rowptr, csr_src, csr_eid, h1, E);

    dim3 g2((N + GT - 1) / GT, 1);
    k_gemm_xwt<<<g2, 256, 0, stream>>>(h1, Wl2, bl2, xl2, N, H1, H2);
    k_gemm_xwt<<<g2, 256, 0, stream>>>(h1, Wr2, br2, xr2, N, H1, H2);

    k_gat_h2<<<N, 64, 0, stream>>>(xl2, xr2, ea, loop_attr, We2, at2, bi2,
                                   rowptr, csr_src, csr_eid, h2, E);

    k_mean<<<128, 256, 0, stream>>>(h2, out, N * H2, 1.0f / (float)N);
}